// Round 1
// 371.530 us; speedup vs baseline: 1.1136x; 1.1136x over previous
//
#include <hip/hip_runtime.h>
#include <math.h>
#include <stdint.h>

#define N_NODES 100000
#define N_EDGES 1600000
#define IN_DIM  256
#define HID     128
#define EPS_C   0.3f
#define NB_SCAN 391   // ceil(N_NODES / 256)

// bucket partition for write-local CSR scatter
#define NPB      128              // nodes per bucket (dst >> 7)
#define NBKT     782              // ceil(N_NODES / NPB)
#define NBKT_P   784              // padded (2 slots per scan thread, 392 used)
#define BCAP     3072             // per-bucket edge capacity (mean 2048, +22 sigma)
#define S1_CHUNK 8192             // edges per partition block
#define S1_BLOCKS 196             // ceil(N_EDGES / S1_CHUNK)

typedef __attribute__((ext_vector_type(8))) __bf16 bf16x8;
typedef __attribute__((ext_vector_type(4))) float  f32x4;
typedef __attribute__((ext_vector_type(8))) unsigned short ushort8;

static __device__ __forceinline__ unsigned short f2bf(float f) {
    unsigned u = __float_as_uint(f);
    unsigned r = (u + 0x7fffu + ((u >> 16) & 1u)) >> 16;
    return (unsigned short)r;
}
static __device__ __forceinline__ float bf2f(unsigned short s) {
    return __uint_as_float((unsigned)s << 16);
}
// branch-free tanh: 1 - 2/(exp2(2x*log2e)+1); correct limits at +-inf
static __device__ __forceinline__ float fast_tanh(float x) {
    float e = __builtin_exp2f(x * 2.8853900817779268f);  // 2*log2(e)
    return 1.0f - 2.0f / (e + 1.0f);
}

// ---------------------------------------------------------------------------
// 1) Count incoming edges per dst (4 edges/thread, int4 reads).
// ---------------------------------------------------------------------------
__global__ __launch_bounds__(256) void count_kernel(const int* __restrict__ dst,
                                                    int* __restrict__ cnt) {
    int i = blockIdx.x * 256 + threadIdx.x;
    if (i * 4 >= N_EDGES) return;
    int4 d = *(const int4*)&dst[i * 4];
    atomicAdd(&cnt[d.x], 1);
    atomicAdd(&cnt[d.y], 1);
    atomicAdd(&cnt[d.z], 1);
    atomicAdd(&cnt[d.w], 1);
}

// ---------------------------------------------------------------------------
// 2) Exclusive scan of cnt -> rowstart; fused nrm write.
// ---------------------------------------------------------------------------
__global__ __launch_bounds__(256) void block_sum_kernel(const int* __restrict__ cnt,
                                                        int* __restrict__ bsum) {
    __shared__ int s[256];
    int t = threadIdx.x;
    int i = blockIdx.x * 256 + t;
    s[t] = (i < N_NODES) ? cnt[i] : 0;
    __syncthreads();
    for (int off = 128; off > 0; off >>= 1) {
        if (t < off) s[t] += s[t + off];
        __syncthreads();
    }
    if (t == 0) bsum[blockIdx.x] = s[0];
}

__global__ __launch_bounds__(512) void scan_bsum_kernel(int* __restrict__ bsum) {
    __shared__ int s[512];
    int t = threadIdx.x;
    int v = (t < NB_SCAN) ? bsum[t] : 0;
    s[t] = v;
    __syncthreads();
    for (int off = 1; off < 512; off <<= 1) {
        int a = (t >= off) ? s[t - off] : 0;
        __syncthreads();
        s[t] += a;
        __syncthreads();
    }
    if (t < NB_SCAN) bsum[t] = s[t] - v;  // exclusive
}

__global__ __launch_bounds__(256) void scan_block_kernel(const int* __restrict__ cnt,
                                                         const int* __restrict__ bsum,
                                                         int* __restrict__ rowstart,
                                                         float* __restrict__ nrm) {
    __shared__ int s[256];
    int t = threadIdx.x;
    int i = blockIdx.x * 256 + t;
    int v = (i < N_NODES) ? cnt[i] : 0;
    s[t] = v;
    __syncthreads();
    for (int off = 1; off < 256; off <<= 1) {
        int a = (t >= off) ? s[t - off] : 0;
        __syncthreads();
        s[t] += a;
        __syncthreads();
    }
    if (i < N_NODES) {
        rowstart[i] = bsum[blockIdx.x] + s[t] - v;
        nrm[i] = rsqrtf(fmaxf((float)v, 1.0f));
    }
    if (i == 0) rowstart[N_NODES] = N_EDGES;
}

// ---------------------------------------------------------------------------
// w1 -> bf16 preconvert (one-time tiny kernel, 32768 elems)
// ---------------------------------------------------------------------------
__global__ __launch_bounds__(256) void convert_w1_kernel(const float* __restrict__ w1,
                                                         unsigned short* __restrict__ w1b) {
    int i = blockIdx.x * 256 + threadIdx.x;
    if (i * 4 >= HID * IN_DIM) return;
    float4 v = *(const float4*)&w1[i * 4];
    ushort4 r;
    r.x = f2bf(v.x); r.y = f2bf(v.y); r.z = f2bf(v.z); r.w = f2bf(v.w);
    *(ushort4*)&w1b[i * 4] = r;
}

// ---------------------------------------------------------------------------
// 3) MFMA GEMM: h = relu(x @ w1^T + b1), bf16, fused gate dots.
//    Block = 256 thr (4 waves), tile M=64 N=128, BK=32, 16x16x32 MFMA.
// ---------------------------------------------------------------------------
__global__ __launch_bounds__(256) void gemm_kernel(const float* __restrict__ x,
                                                   const unsigned short* __restrict__ w1b,
                                                   const float* __restrict__ b1,
                                                   const float* __restrict__ gw,
                                                   const float* __restrict__ nrm,
                                                   unsigned short* __restrict__ h,
                                                   float2* __restrict__ pd_pack,
                                                   float2* __restrict__ ps_pack) {
    __shared__ unsigned short As[64 * 40];   // [m][k] bf16, stride 40
    __shared__ unsigned short Bs[128 * 40];  // [n][k] bf16, stride 40

    int tid = threadIdx.x;
    int bm = blockIdx.x * 64;

    int wv   = tid >> 6;
    int lane = tid & 63;
    int col  = lane & 15;
    int kq   = lane >> 4;

    f32x4 acc[8];
#pragma unroll
    for (int nf = 0; nf < 8; nf++) acc[nf] = (f32x4){0.f, 0.f, 0.f, 0.f};

    int am = tid >> 2;            // 0..63
    int ak = (tid & 3) * 8;       // 0,8,16,24
    int bn = tid >> 1;            // 0..127
    int bk = (tid & 1) * 16;      // 0,16
    int agm = bm + am;

    for (int k0 = 0; k0 < IN_DIM; k0 += 32) {
        // stage A: 64x32 f32 -> bf16 (8 floats/thread)
        float4 a0 = {0,0,0,0}, a1 = {0,0,0,0};
        if (agm < N_NODES) {
            const float* p = &x[agm * IN_DIM + k0 + ak];
            a0 = *(const float4*)p;
            a1 = *(const float4*)(p + 4);
        }
        ushort8 av;
        av[0]=f2bf(a0.x); av[1]=f2bf(a0.y); av[2]=f2bf(a0.z); av[3]=f2bf(a0.w);
        av[4]=f2bf(a1.x); av[5]=f2bf(a1.y); av[6]=f2bf(a1.z); av[7]=f2bf(a1.w);
        // stage B: already bf16 (16 elems = 2 x ushort8 per thread, no convert)
        ushort8 bv0 = *(const ushort8*)&w1b[bn * IN_DIM + k0 + bk];
        ushort8 bv1 = *(const ushort8*)&w1b[bn * IN_DIM + k0 + bk + 8];

        __syncthreads();
        *(ushort8*)&As[am * 40 + ak] = av;
        *(ushort8*)&Bs[bn * 40 + bk] = bv0;
        *(ushort8*)&Bs[bn * 40 + bk + 8] = bv1;
        __syncthreads();

        bf16x8 afrag = *(bf16x8*)&As[(wv * 16 + col) * 40 + kq * 8];
#pragma unroll
        for (int nf = 0; nf < 8; nf++) {
            bf16x8 bfrag = *(bf16x8*)&Bs[(nf * 16 + col) * 40 + kq * 8];
            acc[nf] = __builtin_amdgcn_mfma_f32_16x16x32_bf16(afrag, bfrag, acc[nf], 0, 0, 0);
        }
    }

    float bias[8], wd[8], wsv[8];
#pragma unroll
    for (int nf = 0; nf < 8; nf++) {
        bias[nf] = b1[nf * 16 + col];
        wd[nf]   = gw[nf * 16 + col];
        wsv[nf]  = gw[HID + nf * 16 + col];
    }
#pragma unroll
    for (int r = 0; r < 4; r++) {
        int gm = bm + wv * 16 + kq * 4 + r;   // uniform across the 16 col-lanes
        float pd = 0.f, ps = 0.f;
        bool ok = (gm < N_NODES);
#pragma unroll
        for (int nf = 0; nf < 8; nf++) {
            float v = fmaxf(acc[nf][r] + bias[nf], 0.f);
            pd = fmaf(v, wd[nf], pd);
            ps = fmaf(v, wsv[nf], ps);
            if (ok) h[gm * HID + nf * 16 + col] = f2bf(v);
        }
#pragma unroll
        for (int m = 1; m < 16; m <<= 1) {
            pd += __shfl_xor(pd, m);
            ps += __shfl_xor(ps, m);
        }
        if (ok && col == 0) {
            float nv = nrm[gm];
            pd_pack[gm] = make_float2(pd, nv);
            ps_pack[gm] = make_float2(ps, nv);
        }
    }
}

// ---------------------------------------------------------------------------
// 4a) Partition: bucket-group edges by dst>>7 via LDS counting sort.
//     Coalesced run-writes into ebuf[b*BCAP ...]; one global-cursor atomic
//     per (block, nonempty bucket). Kills the 8x line amplification the old
//     global scatter paid on every 8B write.
// ---------------------------------------------------------------------------
__global__ __launch_bounds__(512) void partition_kernel(const int* __restrict__ src,
                                                        const int* __restrict__ dst,
                                                        int* __restrict__ gcur,
                                                        int2* __restrict__ ebuf) {
    __shared__ int hist[NBKT_P];
    __shared__ int base[NBKT_P];
    __shared__ int gpos[NBKT_P];
    __shared__ int cur[NBKT_P];
    __shared__ int seg[512];
    __shared__ int2 staged[S1_CHUNK];

    int t = threadIdx.x;
    for (int i = t; i < NBKT_P; i += 512) hist[i] = 0;
    __syncthreads();

    int base4 = blockIdx.x * (S1_CHUNK / 4);     // int4 index into src/dst
    int rem4  = N_EDGES / 4 - base4;

    int4 sv[4], dv[4];
#pragma unroll
    for (int j = 0; j < 4; j++) {
        int i4 = j * 512 + t;
        if (i4 < rem4) {
            sv[j] = *(const int4*)&src[(base4 + i4) * 4];
            dv[j] = *(const int4*)&dst[(base4 + i4) * 4];
        } else {
            dv[j] = make_int4(-1, -1, -1, -1);   // sentinel: invalid
        }
    }
#pragma unroll
    for (int j = 0; j < 4; j++) {
        if (dv[j].x >= 0) {
            atomicAdd(&hist[dv[j].x >> 7], 1);
            atomicAdd(&hist[dv[j].y >> 7], 1);
            atomicAdd(&hist[dv[j].z >> 7], 1);
            atomicAdd(&hist[dv[j].w >> 7], 1);
        }
    }
    __syncthreads();

    // block-exclusive scan over NBKT_P buckets: 2 slots per thread (t < 392)
    int h0 = 0, h1 = 0;
    if (t < NBKT_P / 2) { h0 = hist[2 * t]; h1 = hist[2 * t + 1]; }
    seg[t] = h0 + h1;
    __syncthreads();
    for (int off = 1; off < 512; off <<= 1) {
        int a = (t >= off) ? seg[t - off] : 0;
        __syncthreads();
        seg[t] += a;
        __syncthreads();
    }
    if (t < NBKT_P / 2) {
        int excl = seg[t] - (h0 + h1);
        base[2 * t]     = excl;
        cur[2 * t]      = excl;
        base[2 * t + 1] = excl + h0;
        cur[2 * t + 1]  = excl + h0;
        if (h0 > 0) gpos[2 * t]     = atomicAdd(&gcur[2 * t], h0);
        if (h1 > 0) gpos[2 * t + 1] = atomicAdd(&gcur[2 * t + 1], h1);
    }
    __syncthreads();

    // scatter register-held edges into bucket-sorted LDS staging
#pragma unroll
    for (int j = 0; j < 4; j++) {
        if (dv[j].x >= 0) {
            int p;
            p = atomicAdd(&cur[dv[j].x >> 7], 1); staged[p] = make_int2(sv[j].x, dv[j].x);
            p = atomicAdd(&cur[dv[j].y >> 7], 1); staged[p] = make_int2(sv[j].y, dv[j].y);
            p = atomicAdd(&cur[dv[j].z >> 7], 1); staged[p] = make_int2(sv[j].z, dv[j].z);
            p = atomicAdd(&cur[dv[j].w >> 7], 1); staged[p] = make_int2(sv[j].w, dv[j].w);
        }
    }
    __syncthreads();

    // copy out: consecutive i within a bucket -> consecutive global slots
    int n = N_EDGES - base4 * 4;
    if (n > S1_CHUNK) n = S1_CHUNK;
    for (int i = t; i < n; i += 512) {
        int2 e = staged[i];
        int b = e.y >> 7;
        int off2 = gpos[b] + (i - base[b]);
        if (off2 < BCAP) ebuf[(size_t)b * BCAP + off2] = e;
    }
}

// ---------------------------------------------------------------------------
// 4b) Bucket-local CSR scatter: one block per bucket. Slot claims via LDS
//     cursors seeded from rowstart; epack writes land in this bucket's
//     contiguous ~16KB CSR range -> single-L2 full-line writebacks.
// ---------------------------------------------------------------------------
__global__ __launch_bounds__(512) void scatter2_kernel(const int* __restrict__ gcur,
                                                       const int2* __restrict__ ebuf,
                                                       const int* __restrict__ rowstart,
                                                       const float2* __restrict__ pd_pack,
                                                       const float2* __restrict__ ps_pack,
                                                       const float* __restrict__ gb,
                                                       int2* __restrict__ epack) {
    __shared__ int    curs[NPB];
    __shared__ float2 pdl[NPB];
    int b = blockIdx.x;
    int t = threadIdx.x;
    int nbase = b * NPB;
    int nn = N_NODES - nbase;
    if (nn > NPB) nn = NPB;
    if (t < nn) {
        curs[t] = rowstart[nbase + t];
        pdl[t]  = pd_pack[nbase + t];
    }
    __syncthreads();

    int ecnt = gcur[b];
    if (ecnt > BCAP) ecnt = BCAP;
    float gbv = gb[0];
    for (int j = t; j < ecnt; j += 512) {
        int2 e = ebuf[(size_t)b * BCAP + j];
        int li = e.y & (NPB - 1);
        int pos = atomicAdd(&curs[li], 1);
        float2 pdp = pdl[li];               // {a_dst[d], nrm[d]}
        float2 psp = ps_pack[e.x];          // {a_src[s], nrm[s]}
        float g = fast_tanh(pdp.x + psp.x + gbv);
        epack[pos] = make_int2(e.x, __float_as_int(g * pdp.y * psp.y));
    }
}

// ---------------------------------------------------------------------------
// 5) Aggregate: one wave per dst node; 4 edges in parallel per wave
//    (16 lanes x 8 channels each), unroll 2 -> 8 h-rows in flight.
// ---------------------------------------------------------------------------
__global__ __launch_bounds__(256) void aggregate_kernel(const int* __restrict__ rowstart,
                                                        const int2* __restrict__ epack,
                                                        const unsigned short* __restrict__ h,
                                                        float* __restrict__ out) {
    int node = blockIdx.x * 4 + (threadIdx.x >> 6);
    if (node >= N_NODES) return;
    int lane = threadIdx.x & 63;
    int q  = lane >> 4;    // 0..3: edge slot within wave
    int ql = lane & 15;    // channel group: ch = ql*8

    int beg = rowstart[node];
    int end = rowstart[node + 1];

    float acc[8];
#pragma unroll
    for (int t = 0; t < 8; t++) acc[t] = 0.f;

    int j = beg;
    for (; j + 8 <= end; j += 8) {
        int2 e0 = epack[j + q];
        int2 e1 = epack[j + 4 + q];
        ushort8 r0 = *(const ushort8*)&h[e0.x * HID + ql * 8];
        ushort8 r1 = *(const ushort8*)&h[e1.x * HID + ql * 8];
        float c0 = __int_as_float(e0.y);
        float c1 = __int_as_float(e1.y);
#pragma unroll
        for (int t = 0; t < 8; t++) {
            acc[t] = fmaf(c0, bf2f(r0[t]), acc[t]);
            acc[t] = fmaf(c1, bf2f(r1[t]), acc[t]);
        }
    }
    for (; j < end; j += 4) {
        bool act = (j + q) < end;
        int idx = act ? (j + q) : beg;          // beg valid: j<end => beg<end
        int2 e = epack[idx];
        ushort8 r = *(const ushort8*)&h[e.x * HID + ql * 8];
        float c = act ? __int_as_float(e.y) : 0.f;
#pragma unroll
        for (int t = 0; t < 8; t++) acc[t] = fmaf(c, bf2f(r[t]), acc[t]);
    }
    // combine the 4 edge-slots (lane bits 4,5)
#pragma unroll
    for (int t = 0; t < 8; t++) {
        acc[t] += __shfl_xor(acc[t], 16);
        acc[t] += __shfl_xor(acc[t], 32);
    }
    if (q == 0) {
        ushort8 hd = *(const ushort8*)&h[node * HID + ql * 8];
        f32x4 o0, o1;
        o0.x = fmaf(EPS_C, bf2f(hd[0]), acc[0]);
        o0.y = fmaf(EPS_C, bf2f(hd[1]), acc[1]);
        o0.z = fmaf(EPS_C, bf2f(hd[2]), acc[2]);
        o0.w = fmaf(EPS_C, bf2f(hd[3]), acc[3]);
        o1.x = fmaf(EPS_C, bf2f(hd[4]), acc[4]);
        o1.y = fmaf(EPS_C, bf2f(hd[5]), acc[5]);
        o1.z = fmaf(EPS_C, bf2f(hd[6]), acc[6]);
        o1.w = fmaf(EPS_C, bf2f(hd[7]), acc[7]);
        // nontemporal: out is never re-read; keep h resident in L2 instead
        __builtin_nontemporal_store(o0, (f32x4*)&out[node * HID + ql * 8]);
        __builtin_nontemporal_store(o1, (f32x4*)&out[node * HID + ql * 8 + 4]);
    }
}

// ---------------------------------------------------------------------------
extern "C" void kernel_launch(void* const* d_in, const int* in_sizes, int n_in,
                              void* d_out, int out_size, void* d_ws, size_t ws_size,
                              hipStream_t stream) {
    const float* x  = (const float*)d_in[0];
    const int*   ei = (const int*)d_in[1];
    const float* w1 = (const float*)d_in[2];
    const float* b1 = (const float*)d_in[3];
    const float* gw = (const float*)d_in[4];
    const float* gb = (const float*)d_in[5];
    float* out = (float*)d_out;

    const int* src = ei;
    const int* dst = ei + N_EDGES;

    uintptr_t base = (uintptr_t)d_ws;
    size_t off = 0;
    auto alloc = [&](size_t bytes) -> void* {
        void* p = (void*)(base + off);
        off += (bytes + 255) & ~(size_t)255;
        return p;
    };
    unsigned short* h   = (unsigned short*)alloc((size_t)N_NODES * HID * 2);  // 25.6 MB
    float2* pd_pack     = (float2*)alloc((size_t)N_NODES * 8);
    float2* ps_pack     = (float2*)alloc((size_t)N_NODES * 8);
    float*  nrm         = (float*)alloc((size_t)N_NODES * 4);
    int*    cnt         = (int*)alloc((size_t)N_NODES * 4);
    int*    rowstart    = (int*)alloc((size_t)(N_NODES + 1) * 4);
    int2*   epack       = (int2*)alloc((size_t)N_EDGES * 8);
    int*    bsum        = (int*)alloc((size_t)NB_SCAN * 4);
    unsigned short* w1b = (unsigned short*)alloc((size_t)HID * IN_DIM * 2);
    int*    gcur        = (int*)alloc((size_t)NBKT * 4);
    int2*   ebuf        = (int2*)alloc((size_t)NBKT * BCAP * 8);              // 19.2 MB

    (void)hipMemsetAsync(cnt, 0, (size_t)N_NODES * 4, stream);
    (void)hipMemsetAsync(gcur, 0, (size_t)NBKT * 4, stream);

    convert_w1_kernel<<<(HID * IN_DIM / 4 + 255) / 256, 256, 0, stream>>>(w1, w1b);
    count_kernel<<<(N_EDGES / 4 + 255) / 256, 256, 0, stream>>>(dst, cnt);
    block_sum_kernel<<<NB_SCAN, 256, 0, stream>>>(cnt, bsum);
    scan_bsum_kernel<<<1, 512, 0, stream>>>(bsum);
    scan_block_kernel<<<NB_SCAN, 256, 0, stream>>>(cnt, bsum, rowstart, nrm);
    partition_kernel<<<S1_BLOCKS, 512, 0, stream>>>(src, dst, gcur, ebuf);
    gemm_kernel<<<(N_NODES + 63) / 64, 256, 0, stream>>>(x, w1b, b1, gw, nrm,
                                                         h, pd_pack, ps_pack);
    scatter2_kernel<<<NBKT, 512, 0, stream>>>(gcur, ebuf, rowstart,
                                              pd_pack, ps_pack, gb, epack);
    aggregate_kernel<<<(N_NODES + 3) / 4, 256, 0, stream>>>(rowstart, epack, h, out);
}

// Round 2
// 303.091 us; speedup vs baseline: 1.3650x; 1.2258x over previous
//
#include <hip/hip_runtime.h>
#include <math.h>
#include <stdint.h>

#define N_NODES 100000
#define N_EDGES 1600000
#define IN_DIM  256
#define HID     128
#define EPS_C   0.3f

// bucket partition for write-local CSR scatter
#define NPB      128              // nodes per bucket (dst >> 7)
#define NBKT     782              // ceil(N_NODES / NPB)
#define NBKT_P   784              // padded (2 slots per scan thread, 392 used)
#define BCAP     3072             // per-bucket edge capacity (mean 2048, +22 sigma)
#define S1_CHUNK 8192             // edges per partition block
#define S1_BLOCKS 196             // ceil(N_EDGES / S1_CHUNK)

typedef __attribute__((ext_vector_type(8))) __bf16 bf16x8;
typedef __attribute__((ext_vector_type(4))) float  f32x4;
typedef __attribute__((ext_vector_type(8))) unsigned short ushort8;

static __device__ __forceinline__ unsigned short f2bf(float f) {
    unsigned u = __float_as_uint(f);
    unsigned r = (u + 0x7fffu + ((u >> 16) & 1u)) >> 16;
    return (unsigned short)r;
}
static __device__ __forceinline__ float bf2f(unsigned short s) {
    return __uint_as_float((unsigned)s << 16);
}
// branch-free tanh: 1 - 2/(exp2(2x*log2e)+1); correct limits at +-inf
static __device__ __forceinline__ float fast_tanh(float x) {
    float e = __builtin_exp2f(x * 2.8853900817779268f);  // 2*log2(e)
    return 1.0f - 2.0f / (e + 1.0f);
}

// ---------------------------------------------------------------------------
// w1 -> bf16 preconvert (one-time tiny kernel, 32768 elems)
// ---------------------------------------------------------------------------
__global__ __launch_bounds__(256) void convert_w1_kernel(const float* __restrict__ w1,
                                                         unsigned short* __restrict__ w1b) {
    int i = blockIdx.x * 256 + threadIdx.x;
    if (i * 4 >= HID * IN_DIM) return;
    float4 v = *(const float4*)&w1[i * 4];
    ushort4 r;
    r.x = f2bf(v.x); r.y = f2bf(v.y); r.z = f2bf(v.z); r.w = f2bf(v.w);
    *(ushort4*)&w1b[i * 4] = r;
}

// ---------------------------------------------------------------------------
// 1) Partition: bucket-group edges by dst>>7 via LDS counting sort.
//    Coalesced run-writes into ebuf[b*BCAP ...]; one global-cursor atomic
//    per (block, nonempty bucket).
// ---------------------------------------------------------------------------
__global__ __launch_bounds__(512) void partition_kernel(const int* __restrict__ src,
                                                        const int* __restrict__ dst,
                                                        int* __restrict__ gcur,
                                                        int2* __restrict__ ebuf) {
    __shared__ int hist[NBKT_P];
    __shared__ int base[NBKT_P];
    __shared__ int gpos[NBKT_P];
    __shared__ int cur[NBKT_P];
    __shared__ int seg[512];
    __shared__ int2 staged[S1_CHUNK];

    int t = threadIdx.x;
    for (int i = t; i < NBKT_P; i += 512) hist[i] = 0;
    __syncthreads();

    int base4 = blockIdx.x * (S1_CHUNK / 4);     // int4 index into src/dst
    int rem4  = N_EDGES / 4 - base4;

    int4 sv[4], dv[4];
#pragma unroll
    for (int j = 0; j < 4; j++) {
        int i4 = j * 512 + t;
        if (i4 < rem4) {
            sv[j] = *(const int4*)&src[(base4 + i4) * 4];
            dv[j] = *(const int4*)&dst[(base4 + i4) * 4];
        } else {
            dv[j] = make_int4(-1, -1, -1, -1);   // sentinel: invalid
        }
    }
#pragma unroll
    for (int j = 0; j < 4; j++) {
        if (dv[j].x >= 0) {
            atomicAdd(&hist[dv[j].x >> 7], 1);
            atomicAdd(&hist[dv[j].y >> 7], 1);
            atomicAdd(&hist[dv[j].z >> 7], 1);
            atomicAdd(&hist[dv[j].w >> 7], 1);
        }
    }
    __syncthreads();

    // block-exclusive scan over NBKT_P buckets: 2 slots per thread (t < 392)
    int h0 = 0, h1 = 0;
    if (t < NBKT_P / 2) { h0 = hist[2 * t]; h1 = hist[2 * t + 1]; }
    seg[t] = h0 + h1;
    __syncthreads();
    for (int off = 1; off < 512; off <<= 1) {
        int a = (t >= off) ? seg[t - off] : 0;
        __syncthreads();
        seg[t] += a;
        __syncthreads();
    }
    if (t < NBKT_P / 2) {
        int excl = seg[t] - (h0 + h1);
        base[2 * t]     = excl;
        cur[2 * t]      = excl;
        base[2 * t + 1] = excl + h0;
        cur[2 * t + 1]  = excl + h0;
        if (h0 > 0) gpos[2 * t]     = atomicAdd(&gcur[2 * t], h0);
        if (h1 > 0) gpos[2 * t + 1] = atomicAdd(&gcur[2 * t + 1], h1);
    }
    __syncthreads();

    // scatter register-held edges into bucket-sorted LDS staging
#pragma unroll
    for (int j = 0; j < 4; j++) {
        if (dv[j].x >= 0) {
            int p;
            p = atomicAdd(&cur[dv[j].x >> 7], 1); staged[p] = make_int2(sv[j].x, dv[j].x);
            p = atomicAdd(&cur[dv[j].y >> 7], 1); staged[p] = make_int2(sv[j].y, dv[j].y);
            p = atomicAdd(&cur[dv[j].z >> 7], 1); staged[p] = make_int2(sv[j].z, dv[j].z);
            p = atomicAdd(&cur[dv[j].w >> 7], 1); staged[p] = make_int2(sv[j].w, dv[j].w);
        }
    }
    __syncthreads();

    // copy out: consecutive i within a bucket -> consecutive global slots
    int n = N_EDGES - base4 * 4;
    if (n > S1_CHUNK) n = S1_CHUNK;
    for (int i = t; i < n; i += 512) {
        int2 e = staged[i];
        int b = e.y >> 7;
        int off2 = gpos[b] + (i - base[b]);
        if (off2 < BCAP) ebuf[(size_t)b * BCAP + off2] = e;
    }
}

// ---------------------------------------------------------------------------
// 2) Exclusive scan of bucket totals gcur[NBKT] -> bstart (one block).
// ---------------------------------------------------------------------------
__global__ __launch_bounds__(512) void bscan_kernel(const int* __restrict__ gcur,
                                                    int* __restrict__ bstart) {
    __shared__ int s[512];
    int t = threadIdx.x;
    int a0 = 0, a1 = 0;
    if (t < NBKT_P / 2) {
        a0 = (2 * t     < NBKT) ? gcur[2 * t]     : 0;
        a1 = (2 * t + 1 < NBKT) ? gcur[2 * t + 1] : 0;
    }
    s[t] = a0 + a1;
    __syncthreads();
    for (int off = 1; off < 512; off <<= 1) {
        int a = (t >= off) ? s[t - off] : 0;
        __syncthreads();
        s[t] += a;
        __syncthreads();
    }
    if (t < NBKT_P / 2) {
        int excl = s[t] - (a0 + a1);
        if (2 * t     < NBKT) bstart[2 * t]     = excl;
        if (2 * t + 1 < NBKT) bstart[2 * t + 1] = excl + a0;
    }
}

// ---------------------------------------------------------------------------
// 3) Per-bucket degree count -> rowstart + nrm (replaces the old global
//    atomic count + 3-kernel scan chain). Reads the bucket's contiguous
//    ebuf slice (Infinity-Cache resident), LDS-histograms 128 nodes,
//    scans locally, writes rowstart/nrm coalesced.
// ---------------------------------------------------------------------------
__global__ __launch_bounds__(512) void deg_kernel(const int* __restrict__ gcur,
                                                  const int* __restrict__ bstart,
                                                  const int2* __restrict__ ebuf,
                                                  int* __restrict__ rowstart,
                                                  float* __restrict__ nrm) {
    __shared__ int dcnt[NPB];
    __shared__ int s[NPB];
    int b = blockIdx.x;
    int t = threadIdx.x;
    if (t < NPB) dcnt[t] = 0;
    __syncthreads();

    int ecnt = gcur[b];
    if (ecnt > BCAP) ecnt = BCAP;
    for (int j = t; j < ecnt; j += 512) {
        int2 e = ebuf[(size_t)b * BCAP + j];
        atomicAdd(&dcnt[e.y & (NPB - 1)], 1);
    }
    __syncthreads();

    int v = 0;
    if (t < NPB) { v = dcnt[t]; s[t] = v; }
    __syncthreads();
    for (int off = 1; off < NPB; off <<= 1) {
        int a = (t < NPB && t >= off) ? s[t - off] : 0;
        __syncthreads();
        if (t < NPB) s[t] += a;
        __syncthreads();
    }

    int nbase = b * NPB;
    int nn = N_NODES - nbase;
    if (nn > NPB) nn = NPB;
    if (t < nn) {
        rowstart[nbase + t] = bstart[b] + s[t] - v;   // exclusive
        nrm[nbase + t] = rsqrtf(fmaxf((float)v, 1.0f));
    }
    if (b == NBKT - 1 && t == 0) rowstart[N_NODES] = N_EDGES;
}

// ---------------------------------------------------------------------------
// 4) MFMA GEMM: h = relu(x @ w1^T + b1), bf16, fused gate dots.
//    Block = 256 thr (4 waves), tile M=64 N=128, BK=32, 16x16x32 MFMA.
// ---------------------------------------------------------------------------
__global__ __launch_bounds__(256) void gemm_kernel(const float* __restrict__ x,
                                                   const unsigned short* __restrict__ w1b,
                                                   const float* __restrict__ b1,
                                                   const float* __restrict__ gw,
                                                   const float* __restrict__ nrm,
                                                   unsigned short* __restrict__ h,
                                                   float2* __restrict__ pd_pack,
                                                   float2* __restrict__ ps_pack) {
    __shared__ unsigned short As[64 * 40];   // [m][k] bf16, stride 40
    __shared__ unsigned short Bs[128 * 40];  // [n][k] bf16, stride 40

    int tid = threadIdx.x;
    int bm = blockIdx.x * 64;

    int wv   = tid >> 6;
    int lane = tid & 63;
    int col  = lane & 15;
    int kq   = lane >> 4;

    f32x4 acc[8];
#pragma unroll
    for (int nf = 0; nf < 8; nf++) acc[nf] = (f32x4){0.f, 0.f, 0.f, 0.f};

    int am = tid >> 2;            // 0..63
    int ak = (tid & 3) * 8;       // 0,8,16,24
    int bn = tid >> 1;            // 0..127
    int bk = (tid & 1) * 16;      // 0,16
    int agm = bm + am;

    for (int k0 = 0; k0 < IN_DIM; k0 += 32) {
        // stage A: 64x32 f32 -> bf16 (8 floats/thread)
        float4 a0 = {0,0,0,0}, a1 = {0,0,0,0};
        if (agm < N_NODES) {
            const float* p = &x[agm * IN_DIM + k0 + ak];
            a0 = *(const float4*)p;
            a1 = *(const float4*)(p + 4);
        }
        ushort8 av;
        av[0]=f2bf(a0.x); av[1]=f2bf(a0.y); av[2]=f2bf(a0.z); av[3]=f2bf(a0.w);
        av[4]=f2bf(a1.x); av[5]=f2bf(a1.y); av[6]=f2bf(a1.z); av[7]=f2bf(a1.w);
        // stage B: already bf16 (16 elems = 2 x ushort8 per thread, no convert)
        ushort8 bv0 = *(const ushort8*)&w1b[bn * IN_DIM + k0 + bk];
        ushort8 bv1 = *(const ushort8*)&w1b[bn * IN_DIM + k0 + bk + 8];

        __syncthreads();
        *(ushort8*)&As[am * 40 + ak] = av;
        *(ushort8*)&Bs[bn * 40 + bk] = bv0;
        *(ushort8*)&Bs[bn * 40 + bk + 8] = bv1;
        __syncthreads();

        bf16x8 afrag = *(bf16x8*)&As[(wv * 16 + col) * 40 + kq * 8];
#pragma unroll
        for (int nf = 0; nf < 8; nf++) {
            bf16x8 bfrag = *(bf16x8*)&Bs[(nf * 16 + col) * 40 + kq * 8];
            acc[nf] = __builtin_amdgcn_mfma_f32_16x16x32_bf16(afrag, bfrag, acc[nf], 0, 0, 0);
        }
    }

    float bias[8], wd[8], wsv[8];
#pragma unroll
    for (int nf = 0; nf < 8; nf++) {
        bias[nf] = b1[nf * 16 + col];
        wd[nf]   = gw[nf * 16 + col];
        wsv[nf]  = gw[HID + nf * 16 + col];
    }
#pragma unroll
    for (int r = 0; r < 4; r++) {
        int gm = bm + wv * 16 + kq * 4 + r;   // uniform across the 16 col-lanes
        float pd = 0.f, ps = 0.f;
        bool ok = (gm < N_NODES);
#pragma unroll
        for (int nf = 0; nf < 8; nf++) {
            float v = fmaxf(acc[nf][r] + bias[nf], 0.f);
            pd = fmaf(v, wd[nf], pd);
            ps = fmaf(v, wsv[nf], ps);
            if (ok) h[gm * HID + nf * 16 + col] = f2bf(v);
        }
#pragma unroll
        for (int m = 1; m < 16; m <<= 1) {
            pd += __shfl_xor(pd, m);
            ps += __shfl_xor(ps, m);
        }
        if (ok && col == 0) {
            float nv = nrm[gm];
            pd_pack[gm] = make_float2(pd, nv);
            ps_pack[gm] = make_float2(ps, nv);
        }
    }
}

// ---------------------------------------------------------------------------
// 5) Bucket-local CSR scatter: one block per bucket. Slot claims via LDS
//    cursors seeded from rowstart; epack writes land in this bucket's
//    contiguous ~16KB CSR range -> single-L2 full-line writebacks.
// ---------------------------------------------------------------------------
__global__ __launch_bounds__(512) void scatter2_kernel(const int* __restrict__ gcur,
                                                       const int2* __restrict__ ebuf,
                                                       const int* __restrict__ rowstart,
                                                       const float2* __restrict__ pd_pack,
                                                       const float2* __restrict__ ps_pack,
                                                       const float* __restrict__ gb,
                                                       int2* __restrict__ epack) {
    __shared__ int    curs[NPB];
    __shared__ float2 pdl[NPB];
    int b = blockIdx.x;
    int t = threadIdx.x;
    int nbase = b * NPB;
    int nn = N_NODES - nbase;
    if (nn > NPB) nn = NPB;
    if (t < nn) {
        curs[t] = rowstart[nbase + t];
        pdl[t]  = pd_pack[nbase + t];
    }
    __syncthreads();

    int ecnt = gcur[b];
    if (ecnt > BCAP) ecnt = BCAP;
    float gbv = gb[0];
    for (int j = t; j < ecnt; j += 512) {
        int2 e = ebuf[(size_t)b * BCAP + j];
        int li = e.y & (NPB - 1);
        int pos = atomicAdd(&curs[li], 1);
        float2 pdp = pdl[li];               // {a_dst[d], nrm[d]}
        float2 psp = ps_pack[e.x];          // {a_src[s], nrm[s]}
        float g = fast_tanh(pdp.x + psp.x + gbv);
        epack[pos] = make_int2(e.x, __float_as_int(g * pdp.y * psp.y));
    }
}

// ---------------------------------------------------------------------------
// 6) Aggregate: one wave per dst node; 4 edges in parallel per wave
//    (16 lanes x 8 channels each), unroll 2 -> 8 h-rows in flight.
// ---------------------------------------------------------------------------
__global__ __launch_bounds__(256) void aggregate_kernel(const int* __restrict__ rowstart,
                                                        const int2* __restrict__ epack,
                                                        const unsigned short* __restrict__ h,
                                                        float* __restrict__ out) {
    int node = blockIdx.x * 4 + (threadIdx.x >> 6);
    if (node >= N_NODES) return;
    int lane = threadIdx.x & 63;
    int q  = lane >> 4;    // 0..3: edge slot within wave
    int ql = lane & 15;    // channel group: ch = ql*8

    int beg = rowstart[node];
    int end = rowstart[node + 1];

    float acc[8];
#pragma unroll
    for (int t = 0; t < 8; t++) acc[t] = 0.f;

    int j = beg;
    for (; j + 8 <= end; j += 8) {
        int2 e0 = epack[j + q];
        int2 e1 = epack[j + 4 + q];
        ushort8 r0 = *(const ushort8*)&h[e0.x * HID + ql * 8];
        ushort8 r1 = *(const ushort8*)&h[e1.x * HID + ql * 8];
        float c0 = __int_as_float(e0.y);
        float c1 = __int_as_float(e1.y);
#pragma unroll
        for (int t = 0; t < 8; t++) {
            acc[t] = fmaf(c0, bf2f(r0[t]), acc[t]);
            acc[t] = fmaf(c1, bf2f(r1[t]), acc[t]);
        }
    }
    for (; j < end; j += 4) {
        bool act = (j + q) < end;
        int idx = act ? (j + q) : beg;          // beg valid: j<end => beg<end
        int2 e = epack[idx];
        ushort8 r = *(const ushort8*)&h[e.x * HID + ql * 8];
        float c = act ? __int_as_float(e.y) : 0.f;
#pragma unroll
        for (int t = 0; t < 8; t++) acc[t] = fmaf(c, bf2f(r[t]), acc[t]);
    }
    // combine the 4 edge-slots (lane bits 4,5)
#pragma unroll
    for (int t = 0; t < 8; t++) {
        acc[t] += __shfl_xor(acc[t], 16);
        acc[t] += __shfl_xor(acc[t], 32);
    }
    if (q == 0) {
        ushort8 hd = *(const ushort8*)&h[node * HID + ql * 8];
        f32x4 o0, o1;
        o0.x = fmaf(EPS_C, bf2f(hd[0]), acc[0]);
        o0.y = fmaf(EPS_C, bf2f(hd[1]), acc[1]);
        o0.z = fmaf(EPS_C, bf2f(hd[2]), acc[2]);
        o0.w = fmaf(EPS_C, bf2f(hd[3]), acc[3]);
        o1.x = fmaf(EPS_C, bf2f(hd[4]), acc[4]);
        o1.y = fmaf(EPS_C, bf2f(hd[5]), acc[5]);
        o1.z = fmaf(EPS_C, bf2f(hd[6]), acc[6]);
        o1.w = fmaf(EPS_C, bf2f(hd[7]), acc[7]);
        // nontemporal: out is never re-read; keep h resident in L2 instead
        __builtin_nontemporal_store(o0, (f32x4*)&out[node * HID + ql * 8]);
        __builtin_nontemporal_store(o1, (f32x4*)&out[node * HID + ql * 8 + 4]);
    }
}

// ---------------------------------------------------------------------------
extern "C" void kernel_launch(void* const* d_in, const int* in_sizes, int n_in,
                              void* d_out, int out_size, void* d_ws, size_t ws_size,
                              hipStream_t stream) {
    const float* x  = (const float*)d_in[0];
    const int*   ei = (const int*)d_in[1];
    const float* w1 = (const float*)d_in[2];
    const float* b1 = (const float*)d_in[3];
    const float* gw = (const float*)d_in[4];
    const float* gb = (const float*)d_in[5];
    float* out = (float*)d_out;

    const int* src = ei;
    const int* dst = ei + N_EDGES;

    uintptr_t base = (uintptr_t)d_ws;
    size_t off = 0;
    auto alloc = [&](size_t bytes) -> void* {
        void* p = (void*)(base + off);
        off += (bytes + 255) & ~(size_t)255;
        return p;
    };
    unsigned short* h   = (unsigned short*)alloc((size_t)N_NODES * HID * 2);  // 25.6 MB
    float2* pd_pack     = (float2*)alloc((size_t)N_NODES * 8);
    float2* ps_pack     = (float2*)alloc((size_t)N_NODES * 8);
    float*  nrm         = (float*)alloc((size_t)N_NODES * 4);
    int*    rowstart    = (int*)alloc((size_t)(N_NODES + 1) * 4);
    int2*   epack       = (int2*)alloc((size_t)N_EDGES * 8);
    unsigned short* w1b = (unsigned short*)alloc((size_t)HID * IN_DIM * 2);
    int*    gcur        = (int*)alloc((size_t)NBKT * 4);
    int*    bstart      = (int*)alloc((size_t)NBKT * 4);
    int2*   ebuf        = (int2*)alloc((size_t)NBKT * BCAP * 8);              // 19.2 MB

    (void)hipMemsetAsync(gcur, 0, (size_t)NBKT * 4, stream);

    convert_w1_kernel<<<(HID * IN_DIM / 4 + 255) / 256, 256, 0, stream>>>(w1, w1b);
    partition_kernel<<<S1_BLOCKS, 512, 0, stream>>>(src, dst, gcur, ebuf);
    bscan_kernel<<<1, 512, 0, stream>>>(gcur, bstart);
    deg_kernel<<<NBKT, 512, 0, stream>>>(gcur, bstart, ebuf, rowstart, nrm);
    gemm_kernel<<<(N_NODES + 63) / 64, 256, 0, stream>>>(x, w1b, b1, gw, nrm,
                                                         h, pd_pack, ps_pack);
    scatter2_kernel<<<NBKT, 512, 0, stream>>>(gcur, ebuf, rowstart,
                                              pd_pack, ps_pack, gb, epack);
    aggregate_kernel<<<(N_NODES + 3) / 4, 256, 0, stream>>>(rowstart, epack, h, out);
}